// Round 1
// baseline (2089.949 us; speedup 1.0000x reference)
//
#include <hip/hip_runtime.h>
#include <stdint.h>

constexpr int Bc = 4096;
constexpr int Kc = 32;
constexpr int Dc = 1024;
constexpr int Rc = 128;
constexpr int MNB = Bc * Kc;          // 131072 neighbor rows

typedef __attribute__((ext_vector_type(8))) short short8;
typedef __attribute__((ext_vector_type(4))) float floatx4;

__device__ __forceinline__ unsigned short f2bf(float x) {
  union { float f; uint32_t u; } v; v.f = x;
  return (unsigned short)((v.u + 0x7fffu + ((v.u >> 16) & 1u)) >> 16);
}
__device__ __forceinline__ float bf2f(unsigned short b) {
  union { float f; uint32_t u; } v; v.u = ((uint32_t)b) << 16;
  return v.f;
}

__device__ __forceinline__ void async_copy16(const void* g, void* l) {
  __builtin_amdgcn_global_load_lds(
      (const __attribute__((address_space(1))) void*)g,
      (__attribute__((address_space(3))) void*)l, 16, 0, 0);
}

// ---------------------------------------------------------------------------
// K1: fused LayerNorm of target (rows 0..4095) and neighbors -> bf16
// one block per row of 1024
// ---------------------------------------------------------------------------
__global__ __launch_bounds__(256) void ln_kernel(
    const float* __restrict__ target, const float* __restrict__ neighbors,
    const float* __restrict__ scale, const float* __restrict__ bias,
    unsigned short* __restrict__ tc_bf, unsigned short* __restrict__ nb_bf) {
  int row = blockIdx.x;
  const float* src;
  unsigned short* dst;
  if (row < Bc) {
    src = target + (size_t)row * Dc;
    dst = tc_bf + (size_t)row * Dc;
  } else {
    size_t r2 = (size_t)(row - Bc);
    src = neighbors + r2 * Dc;
    dst = nb_bf + r2 * Dc;
  }
  int t = threadIdx.x;
  float4 x = ((const float4*)src)[t];
  float s = x.x + x.y + x.z + x.w;
  float ss = x.x * x.x + x.y * x.y + x.z * x.z + x.w * x.w;
#pragma unroll
  for (int m = 32; m >= 1; m >>= 1) {
    s += __shfl_xor(s, m, 64);
    ss += __shfl_xor(ss, m, 64);
  }
  __shared__ float red[8];
  int wave = t >> 6, lane = t & 63;
  if (lane == 0) { red[wave] = s; red[wave + 4] = ss; }
  __syncthreads();
  s = red[0] + red[1] + red[2] + red[3];
  ss = red[4] + red[5] + red[6] + red[7];
  float mu = s * (1.0f / Dc);
  float var = ss * (1.0f / Dc) - mu * mu;
  float rstd = rsqrtf(var + 1e-5f);
  float4 sc = ((const float4*)scale)[t];
  float4 bi = ((const float4*)bias)[t];
  ushort4 o;
  o.x = f2bf((x.x - mu) * rstd * sc.x + bi.x);
  o.y = f2bf((x.y - mu) * rstd * sc.y + bi.y);
  o.z = f2bf((x.z - mu) * rstd * sc.z + bi.z);
  o.w = f2bf((x.w - mu) * rstd * sc.w + bi.w);
  ((ushort4*)dst)[t] = o;
}

// ---------------------------------------------------------------------------
// K2: f32 -> bf16 converter (for weight matrices)
// ---------------------------------------------------------------------------
__global__ __launch_bounds__(256) void conv_kernel(
    const float* __restrict__ src, unsigned short* __restrict__ dst, int n4) {
  int i = blockIdx.x * 256 + threadIdx.x;
  if (i < n4) {
    float4 x = ((const float4*)src)[i];
    ushort4 o;
    o.x = f2bf(x.x); o.y = f2bf(x.y); o.z = f2bf(x.z); o.w = f2bf(x.w);
    ((ushort4*)dst)[i] = o;
  }
}

// ---------------------------------------------------------------------------
// GEMM: C[m,n] = sum_k A[m,k] * B[n,k] + bias[n]   (NT, both row-major, ld=Kd)
// bf16 inputs, f32 out. 128x128 tile, BK=64, 256 threads (4 waves 2x2),
// each wave 4x4 grid of 16x16x32 MFMAs. global_load_lds width-16 staging.
// EPI: 0 = plain +bias, 1 = +bias then leaky_relu(0.01)
// ---------------------------------------------------------------------------
template <int EPI>
__global__ __launch_bounds__(256) void gemm_bf16(
    const unsigned short* __restrict__ A, const unsigned short* __restrict__ Bm,
    const float* __restrict__ bias, float* __restrict__ C,
    int M, int N, int Kd, int NN, int NMdiv8) {
  __shared__ short Alds[128 * 64];
  __shared__ short Blds[128 * 64];

  // XCD-aware swizzle: each XCD gets a contiguous M-slab, bn iterates fastest
  int g = blockIdx.x;
  int xcd = g & 7;
  int t = g >> 3;
  int bn = t % NN;
  int bm = xcd * NMdiv8 + t / NN;

  int tid = threadIdx.x;
  int wave = tid >> 6;
  int lane = tid & 63;
  int wm = (wave >> 1) * 64;
  int wn = (wave & 1) * 64;

  floatx4 acc[4][4];
#pragma unroll
  for (int mi = 0; mi < 4; ++mi)
#pragma unroll
    for (int ni = 0; ni < 4; ++ni) {
      floatx4 z = {0.f, 0.f, 0.f, 0.f};
      acc[mi][ni] = z;
    }

  int srow = lane >> 3;          // 0..7 row within an 8-row staging group
  int scol = (lane & 7) * 8;     // element col within BK=64
  size_t lda = (size_t)Kd;

  for (int k0 = 0; k0 < Kd; k0 += 64) {
#pragma unroll
    for (int i = 0; i < 4; ++i) {
      int grp = wave * 4 + i;                 // 0..15, 8 rows each
      int rA = grp * 8 + srow;                // 0..127 within tile
      const unsigned short* gA = A + ((size_t)(bm * 128 + rA)) * lda + k0 + scol;
      const unsigned short* gB = Bm + ((size_t)(bn * 128 + rA)) * lda + k0 + scol;
      async_copy16(gA, &Alds[grp * 512]);
      async_copy16(gB, &Blds[grp * 512]);
    }
    __syncthreads();
#pragma unroll
    for (int ks = 0; ks < 2; ++ks) {
      short8 af[4], bf[4];
#pragma unroll
      for (int mi = 0; mi < 4; ++mi)
        af[mi] = *(const short8*)&Alds[(wm + mi * 16 + (lane & 15)) * 64 +
                                       ks * 32 + (lane >> 4) * 8];
#pragma unroll
      for (int ni = 0; ni < 4; ++ni)
        bf[ni] = *(const short8*)&Blds[(wn + ni * 16 + (lane & 15)) * 64 +
                                       ks * 32 + (lane >> 4) * 8];
#pragma unroll
      for (int mi = 0; mi < 4; ++mi)
#pragma unroll
        for (int ni = 0; ni < 4; ++ni)
          acc[mi][ni] = __builtin_amdgcn_mfma_f32_16x16x32_bf16(
              af[mi], bf[ni], acc[mi][ni], 0, 0, 0);
    }
    __syncthreads();
  }

  // epilogue: C/D layout col=lane&15, row=(lane>>4)*4+r
  int quad = lane >> 4;
  int col15 = lane & 15;
#pragma unroll
  for (int mi = 0; mi < 4; ++mi) {
#pragma unroll
    for (int ni = 0; ni < 4; ++ni) {
      int n_g = bn * 128 + wn + ni * 16 + col15;
      float bv = bias[n_g];
#pragma unroll
      for (int r = 0; r < 4; ++r) {
        int m_g = bm * 128 + wm + mi * 16 + quad * 4 + r;
        float v = acc[mi][ni][r] + bv;
        if (EPI == 1) v = (v > 0.f) ? v : 0.01f * v;
        C[(size_t)m_g * N + n_g] = v;
      }
    }
  }
}

// ---------------------------------------------------------------------------
// K3: per (b,d): softmax over [self_score, nb_score[k]*dist_w[k]] (33 logits),
// threshold at 0.01, write weights IN PLACE over the score buffers,
// accumulate context -> bf16.
// one block per b; thread t handles d = t + 256*j, j=0..3
// ---------------------------------------------------------------------------
__global__ __launch_bounds__(256) void softmax_ctx_kernel(
    const float* __restrict__ distances, const float* __restrict__ beta_p,
    const unsigned short* __restrict__ tc_bf,
    const unsigned short* __restrict__ nb_bf,
    float* __restrict__ selfw, float* __restrict__ nbw,
    unsigned short* __restrict__ ctx_bf) {
  int b = blockIdx.x;
  int t = threadIdx.x;
  __shared__ float dw_s[Kc];
  if (t < Kc) {
    // exp(-ALPHA * d / (RADIUS + 1e-8)), ALPHA=2, RADIUS=100
    dw_s[t] = __expf((float)(-2.0 / 100.00000001) * distances[(size_t)b * Kc + t]);
  }
  __syncthreads();
  float beta = beta_p[0];
  float omb = 1.0f - beta;

#pragma unroll
  for (int j = 0; j < 4; ++j) {
    int d = t + 256 * j;
    size_t base = (size_t)b * Dc + d;
    float l0 = selfw[base];
    float mx = l0;
    float lk[Kc];
#pragma unroll
    for (int k = 0; k < Kc; ++k) {
      float sres = nbw[((size_t)(b * Kc + k)) * Dc + d];
      float l = sres * dw_s[k];
      lk[k] = l;
      mx = fmaxf(mx, l);
    }
    float e0 = __expf(l0 - mx);
    float sum = e0;
#pragma unroll
    for (int k = 0; k < Kc; ++k) {
      float e = __expf(lk[k] - mx);
      lk[k] = e;
      sum += e;
    }
    float inv = 1.0f / sum;
    float w0 = e0 * inv;
    if (w0 < 0.01f) w0 = 0.0f;
    selfw[base] = w0;
    float ctx = beta * w0 * bf2f(tc_bf[base]);
#pragma unroll
    for (int k = 0; k < Kc; ++k) {
      float w = lk[k] * inv;
      if (w < 0.01f) w = 0.0f;
      size_t idx = ((size_t)(b * Kc + k)) * Dc + d;
      nbw[idx] = w;
      ctx += omb * w * bf2f(nb_bf[idx]);
    }
    ctx_bf[base] = f2bf(ctx);
  }
}

// ---------------------------------------------------------------------------
extern "C" void kernel_launch(void* const* d_in, const int* in_sizes, int n_in,
                              void* d_out, int out_size, void* d_ws,
                              size_t ws_size, hipStream_t stream) {
  const float* target    = (const float*)d_in[0];
  const float* neighbors = (const float*)d_in[1];
  const float* distances = (const float*)d_in[2];
  const float* beta      = (const float*)d_in[3];
  const float* ln_scale  = (const float*)d_in[4];
  const float* ln_bias   = (const float*)d_in[5];
  const float* w_self    = (const float*)d_in[6];
  const float* b_self    = (const float*)d_in[7];
  const float* w_nb      = (const float*)d_in[8];
  const float* b_nb      = (const float*)d_in[9];
  const float* w_red     = (const float*)d_in[10];
  const float* b_red     = (const float*)d_in[11];

  float* out = (float*)d_out;
  float* reduced = out;                          // 4096*128
  float* selfw   = out + (size_t)Bc * Rc;        // 4096*1024
  float* nbw     = selfw + (size_t)Bc * Dc;      // 131072*1024 (scores then weights)

  char* ws = (char*)d_ws;
  unsigned short* nb_bf   = (unsigned short*)ws;                      // 268435456 B
  unsigned short* tc_bf   = (unsigned short*)(ws + 268435456);        // 8388608 B
  unsigned short* ctx_bf  = (unsigned short*)(ws + 276824064);        // 8388608 B
  unsigned short* wself_bf = (unsigned short*)(ws + 285212672);       // 2097152 B
  unsigned short* wnb_bf   = (unsigned short*)(ws + 287309824);       // 2097152 B
  unsigned short* wred_bf  = (unsigned short*)(ws + 289406976);       // 262144 B

  // 1. LayerNorm target + neighbors -> bf16
  ln_kernel<<<Bc + MNB, 256, 0, stream>>>(target, neighbors, ln_scale, ln_bias,
                                          tc_bf, nb_bf);
  // 2. weight conversions
  conv_kernel<<<1024, 256, 0, stream>>>(w_self, wself_bf, 262144);
  conv_kernel<<<1024, 256, 0, stream>>>(w_nb, wnb_bf, 262144);
  conv_kernel<<<128, 256, 0, stream>>>(w_red, wred_bf, 32768);
  // 3. self scores: (4096x1024) @ (1024x1024)^T -> selfw region
  gemm_bf16<0><<<256, 256, 0, stream>>>(tc_bf, wself_bf, b_self, selfw,
                                        Bc, Dc, Dc, 8, 4);
  // 4. neighbor scores: (131072x1024) @ (1024x1024)^T -> nbw region
  gemm_bf16<0><<<8192, 256, 0, stream>>>(nb_bf, wnb_bf, b_nb, nbw,
                                         MNB, Dc, Dc, 8, 128);
  // 5. softmax + threshold + context (in-place score->weight)
  softmax_ctx_kernel<<<Bc, 256, 0, stream>>>(distances, beta, tc_bf, nb_bf,
                                             selfw, nbw, ctx_bf);
  // 6. reduced: (4096x1024) @ (128x1024)^T + bias, leaky -> reduced region
  gemm_bf16<1><<<32, 256, 0, stream>>>(ctx_bf, wred_bf, b_red, reduced,
                                       Bc, Rc, Dc, 1, 4);
}